// Round 19
// baseline (59.630 us; speedup 1.0000x reference)
//
#include <hip/hip_runtime.h>
#include <hip/hip_bf16.h>
#include <math.h>

#define NDIM 4096
#define MDIM 4096
#define LDIM 512
#define KDIM 1024

typedef float f32x16 __attribute__((ext_vector_type(16)));

// Transposed-blocked fp8 operands: [k>>3][point][k&7] -> u64 per (octet,point)
__device__ __align__(16) unsigned long long g_At[(size_t)128 * NDIM];
__device__ __align__(16) unsigned long long g_Bt[(size_t)128 * MDIM];

// ---------------------------------------------------------------------------
// Phase kernel (R13 verbatim -- proven fp8 encoding): thread -> (point p,
// octet o); 8 l's each; cos-octet -> k-octet o, sin-octet -> k-octet o+64,
// fp8 e4m3 packed 8B. A rows weighted by w_l ONLY (values in [-1,1]; s NOT
// folded in -- fp8 subnormal trap, R17). B cols unweighted. Coalesced stores.
// ---------------------------------------------------------------------------
__global__ __launch_bounds__(256) void phase_kernel(const float* __restrict__ x,
                                                    const float* __restrict__ y,
                                                    const float* __restrict__ freqs,
                                                    const float* __restrict__ lam) {
  int tid = threadIdx.x;
  int blk = blockIdx.x;
  int p = (blk & 127) * 64 + (tid & 63);
  int o = (blk >> 7) * 4 + (tid >> 6);
  bool isA = (p < NDIM);
  int rr = isA ? p : (p - NDIM);
  const float* pt = (isA ? x : y) + 3 * (size_t)rr;
  float p0 = pt[0], p1 = pt[1], p2 = pt[2];

  float cv[8], sv[8];
  #pragma unroll
  for (int i = 0; i < 8; ++i) {
    int li = o * 8 + i;
    float px = p0 * freqs[3 * li] + p1 * freqs[3 * li + 1] + p2 * freqs[3 * li + 2];
    float sn, cs;
    __sincosf(px, &sn, &cs);
    float wl = isA ? expf(-0.5f * lam[li]) : 1.0f;
    cv[i] = cs * wl;
    sv[i] = sn * wl;
  }
  union { int i2[2]; unsigned long long u; } pc, ps;
  pc.i2[0] = __builtin_amdgcn_cvt_pk_fp8_f32(cv[0], cv[1], 0, 0);
  pc.i2[0] = __builtin_amdgcn_cvt_pk_fp8_f32(cv[2], cv[3], pc.i2[0], 1);
  pc.i2[1] = __builtin_amdgcn_cvt_pk_fp8_f32(cv[4], cv[5], 0, 0);
  pc.i2[1] = __builtin_amdgcn_cvt_pk_fp8_f32(cv[6], cv[7], pc.i2[1], 1);
  ps.i2[0] = __builtin_amdgcn_cvt_pk_fp8_f32(sv[0], sv[1], 0, 0);
  ps.i2[0] = __builtin_amdgcn_cvt_pk_fp8_f32(sv[2], sv[3], ps.i2[0], 1);
  ps.i2[1] = __builtin_amdgcn_cvt_pk_fp8_f32(sv[4], sv[5], 0, 0);
  ps.i2[1] = __builtin_amdgcn_cvt_pk_fp8_f32(sv[6], sv[7], ps.i2[1], 1);

  unsigned long long* base = (isA ? g_At : g_Bt) + rr;
  base[(size_t)o * NDIM]        = pc.u;   // k-octet o       (cos)
  base[(size_t)(o + 64) * NDIM] = ps.u;   // k-octet o + 64  (sin)
}

// ---------------------------------------------------------------------------
// GEMM: C = s*(A @ B^T), fp8 e4m3, K=1024, 32x32x16 MFMA. R18 skeleton
// (barrier-free, no-LDS, 256x256 tile, 8 waves 2Mx4N, wave-tile 128x64,
// depth-2 prefetch 3 named buffers, setprio, s-prologue + f32 epilogue).
// Shape change: 512 MFMA/wave (was 1024) at the higher 32x32 rate; fragment
// loads become 2x256B segments; A/B lane map: point = lane&31, k-oct add
// lane>>5. acc = 4x2 f32x16 = 128 AGPR. C/D: col=lane&31,
// row=(reg&3)+8*(reg>>2)+4*(lane>>5)  [m74/m101].
// ---------------------------------------------------------------------------
__global__ __launch_bounds__(512, 2) void gemm_kernel(float* __restrict__ C,
                                                      const float* __restrict__ lam,
                                                      const float* __restrict__ var) {
  __shared__ float red[8];

  int bid = blockIdx.x;                   // 0..255
  int xcd = bid & 7;                      // supertile map (R10/R12/R13)
  int slt = bid >> 3;
  int sup = 2 * xcd + (slt >> 4);
  int w_  = slt & 15;
  int brow = ((sup >> 2) * 4 + (w_ >> 2)) * 256;
  int bcol = ((sup & 3) * 4 + (w_ & 3)) * 256;

  int tid  = threadIdx.x;
  int lane = tid & 63;
  int wid  = tid >> 6;                    // 0..7
  int wm   = wid >> 2;                    // 0..1
  int wn   = wid & 3;                     // 0..3
  int lp   = lane & 31;                   // point-in-frag
  int kh   = lane >> 5;                   // k-octet half (0,1)

  // ---- s-prologue: s = |var| / sum_l exp(-0.5*lam_l)  (tid < 512 = LDIM) ----
  float v_ = expf(-0.5f * lam[tid]);
  #pragma unroll
  for (int off = 32; off > 0; off >>= 1) v_ += __shfl_down(v_, off, 64);
  if (lane == 0) red[wid] = v_;
  __syncthreads();
  float s_val = fabsf(var[0]) / (red[0] + red[1] + red[2] + red[3] +
                                 red[4] + red[5] + red[6] + red[7]);

  // bases: half-tile H covers k-octets 4H..4H+3; k-step s uses 4H+2s+kh
  const unsigned long long* At = g_At + (size_t)kh * NDIM + (brow + wm * 128 + lp);
  const unsigned long long* Bt = g_Bt + (size_t)kh * MDIM + (bcol + wn * 64 + lp);

  f32x16 acc[4][2] = {};
  // per buffer: A frags a0-3 (s=0, mi 0-3), a4-7 (s=1); B frags b0,b1 (s=0,
  // ni 0,1), b2,b3 (s=1)
  long Aa0, Aa1, Aa2, Aa3, Aa4, Aa5, Aa6, Aa7, Ab0, Ab1, Ab2, Ab3;  // buf A
  long Ba0, Ba1, Ba2, Ba3, Ba4, Ba5, Ba6, Ba7, Bb0, Bb1, Bb2, Bb3;  // buf B
  long Ca0, Ca1, Ca2, Ca3, Ca4, Ca5, Ca6, Ca7, Cb0, Cb1, Cb2, Cb3;  // buf C

#define LOADH(S, H)                                                          \
  { const unsigned long long* Ap_ = At + (size_t)(H) * 4 * NDIM;             \
    const unsigned long long* Aq_ = Ap_ + (size_t)2 * NDIM;                  \
    const unsigned long long* Bp_ = Bt + (size_t)(H) * 4 * MDIM;             \
    const unsigned long long* Bq_ = Bp_ + (size_t)2 * MDIM;                  \
    S##a0 = (long)Ap_[0];   S##a1 = (long)Ap_[32];                           \
    S##a2 = (long)Ap_[64];  S##a3 = (long)Ap_[96];                           \
    S##a4 = (long)Aq_[0];   S##a5 = (long)Aq_[32];                           \
    S##a6 = (long)Aq_[64];  S##a7 = (long)Aq_[96];                           \
    S##b0 = (long)Bp_[0];   S##b1 = (long)Bp_[32];                           \
    S##b2 = (long)Bq_[0];   S##b3 = (long)Bq_[32]; }

#define MF32(MI, NI, AF, BF)                                                 \
  acc[MI][NI] = __builtin_amdgcn_mfma_f32_32x32x16_fp8_fp8(AF, BF, acc[MI][NI], 0, 0, 0);

#define MFH(S)                                                               \
  __builtin_amdgcn_s_setprio(1);                                             \
  MF32(0, 0, S##a0, S##b0) MF32(0, 1, S##a0, S##b1)                          \
  MF32(1, 0, S##a1, S##b0) MF32(1, 1, S##a1, S##b1)                          \
  MF32(2, 0, S##a2, S##b0) MF32(2, 1, S##a2, S##b1)                          \
  MF32(3, 0, S##a3, S##b0) MF32(3, 1, S##a3, S##b1)                          \
  MF32(0, 0, S##a4, S##b2) MF32(0, 1, S##a4, S##b3)                          \
  MF32(1, 0, S##a5, S##b2) MF32(1, 1, S##a5, S##b3)                          \
  MF32(2, 0, S##a6, S##b2) MF32(2, 1, S##a6, S##b3)                          \
  MF32(3, 0, S##a7, S##b2) MF32(3, 1, S##a7, S##b3)                          \
  __builtin_amdgcn_s_setprio(0);

  // ---- depth-2 software pipeline over 32 half-tiles (buffers A,B,C) ----
  LOADH(A, 0);
  LOADH(B, 1);
  for (int i = 0; i < 10; ++i) {
    int hs = 3 * i;
    LOADH(C, hs + 2);
    MFH(A);
    LOADH(A, hs + 3);
    MFH(B);
    LOADH(B, hs + 4);
    MFH(C);
  }
  MFH(A);
  MFH(B);

  // ---- epilogue: out = s*acc; C/D col=lane&31, row=(r&3)+8*(r>>2)+4*kh ----
  int ccol = bcol + wn * 64 + lp;
  int crow = brow + wm * 128 + 4 * kh;
  #pragma unroll
  for (int mi = 0; mi < 4; ++mi)
    #pragma unroll
    for (int ni = 0; ni < 2; ++ni)
      #pragma unroll
      for (int r = 0; r < 16; ++r) {
        int row = crow + mi * 32 + (r & 3) + 8 * (r >> 2);
        C[(size_t)row * MDIM + (ccol + ni * 32)] = s_val * acc[mi][ni][r];
      }
}

extern "C" void kernel_launch(void* const* d_in, const int* in_sizes, int n_in,
                              void* d_out, int out_size, void* d_ws, size_t ws_size,
                              hipStream_t stream) {
  const float* x     = (const float*)d_in[0];
  const float* y     = (const float*)d_in[1];
  const float* freqs = (const float*)d_in[2];
  const float* lam   = (const float*)d_in[3];
  const float* var   = (const float*)d_in[4];
  float* out = (float*)d_out;

  hipLaunchKernelGGL(phase_kernel, dim3(2048), dim3(256), 0, stream,
                     x, y, freqs, lam);
  hipLaunchKernelGGL(gemm_kernel, dim3((NDIM / 256) * (MDIM / 256)), dim3(512), 0, stream,
                     out, lam, var);
}

// Round 20
// 48.387 us; speedup vs baseline: 1.2324x; 1.2324x over previous
//
#include <hip/hip_runtime.h>
#include <hip/hip_bf16.h>
#include <math.h>

#define NDIM 4096
#define MDIM 4096
#define LDIM 512
#define KDIM 1024

typedef float f32x4 __attribute__((ext_vector_type(4)));

// Transposed-blocked fp8 operands: [k>>3][point][k&7] -> u64 per (octet,point)
__device__ __align__(16) unsigned long long g_At[(size_t)128 * NDIM];
__device__ __align__(16) unsigned long long g_Bt[(size_t)128 * MDIM];

// ---------------------------------------------------------------------------
// Phase kernel (R13 verbatim -- the proven-passing fp8 encoding): thread ->
// (point p, octet o); 8 l's each; cos-octet -> k-octet o, sin-octet ->
// k-octet o+64, fp8 e4m3 packed 8B. A rows weighted by w_l ONLY (values in
// [-1,1]; s is NOT folded in -- fp8 subnormal trap, see R17 post-mortem).
// B cols unweighted. Coalesced 512B/wave stores.
// ---------------------------------------------------------------------------
__global__ __launch_bounds__(256) void phase_kernel(const float* __restrict__ x,
                                                    const float* __restrict__ y,
                                                    const float* __restrict__ freqs,
                                                    const float* __restrict__ lam) {
  int tid = threadIdx.x;
  int blk = blockIdx.x;
  int p = (blk & 127) * 64 + (tid & 63);
  int o = (blk >> 7) * 4 + (tid >> 6);
  bool isA = (p < NDIM);
  int rr = isA ? p : (p - NDIM);
  const float* pt = (isA ? x : y) + 3 * (size_t)rr;
  float p0 = pt[0], p1 = pt[1], p2 = pt[2];

  float cv[8], sv[8];
  #pragma unroll
  for (int i = 0; i < 8; ++i) {
    int li = o * 8 + i;
    float px = p0 * freqs[3 * li] + p1 * freqs[3 * li + 1] + p2 * freqs[3 * li + 2];
    float sn, cs;
    __sincosf(px, &sn, &cs);
    float wl = isA ? expf(-0.5f * lam[li]) : 1.0f;
    cv[i] = cs * wl;
    sv[i] = sn * wl;
  }
  union { int i2[2]; unsigned long long u; } pc, ps;
  pc.i2[0] = __builtin_amdgcn_cvt_pk_fp8_f32(cv[0], cv[1], 0, 0);
  pc.i2[0] = __builtin_amdgcn_cvt_pk_fp8_f32(cv[2], cv[3], pc.i2[0], 1);
  pc.i2[1] = __builtin_amdgcn_cvt_pk_fp8_f32(cv[4], cv[5], 0, 0);
  pc.i2[1] = __builtin_amdgcn_cvt_pk_fp8_f32(cv[6], cv[7], pc.i2[1], 1);
  ps.i2[0] = __builtin_amdgcn_cvt_pk_fp8_f32(sv[0], sv[1], 0, 0);
  ps.i2[0] = __builtin_amdgcn_cvt_pk_fp8_f32(sv[2], sv[3], ps.i2[0], 1);
  ps.i2[1] = __builtin_amdgcn_cvt_pk_fp8_f32(sv[4], sv[5], 0, 0);
  ps.i2[1] = __builtin_amdgcn_cvt_pk_fp8_f32(sv[6], sv[7], ps.i2[1], 1);

  unsigned long long* base = (isA ? g_At : g_Bt) + rr;
  base[(size_t)o * NDIM]        = pc.u;   // k-octet o       (cos)
  base[(size_t)(o + 64) * NDIM] = ps.u;   // k-octet o + 64  (sin)
}

// ---------------------------------------------------------------------------
// GEMM: C = s*(A @ B^T), fp8 e4m3, K=1024, 16x16x32 MFMA. R18 frozen design:
// barrier-free, no-LDS, 256x256 tile, 8 waves 2Mx4N, wave-tile 128x64,
// coalesced b64 fragment loads, depth-2 prefetch (3 named buffers,
// x3-unrolled rotation), setprio(1) around each 32-MFMA cluster; s-prologue
// (one expf + reduce + one __syncthreads) with s applied in the f32 epilogue.
// ---------------------------------------------------------------------------
__global__ __launch_bounds__(512, 2) void gemm_kernel(float* __restrict__ C,
                                                      const float* __restrict__ lam,
                                                      const float* __restrict__ var) {
  __shared__ float red[8];

  int bid = blockIdx.x;                   // 0..255
  int xcd = bid & 7;                      // supertile map (R10/R12/R13)
  int slt = bid >> 3;
  int sup = 2 * xcd + (slt >> 4);
  int w_  = slt & 15;
  int brow = ((sup >> 2) * 4 + (w_ >> 2)) * 256;
  int bcol = ((sup & 3) * 4 + (w_ & 3)) * 256;

  int tid  = threadIdx.x;
  int lane = tid & 63;
  int wid  = tid >> 6;                    // 0..7
  int wm   = wid >> 2;                    // 0..1
  int wn   = wid & 3;                     // 0..3
  int fr   = lane & 15;
  int oct  = lane >> 4;                   // 0..3

  // ---- s-prologue: s = |var| / sum_l exp(-0.5*lam_l)  (tid < 512 = LDIM) ----
  float v_ = expf(-0.5f * lam[tid]);
  #pragma unroll
  for (int off = 32; off > 0; off >>= 1) v_ += __shfl_down(v_, off, 64);
  if (lane == 0) red[wid] = v_;
  __syncthreads();
  float s_val = fabsf(var[0]) / (red[0] + red[1] + red[2] + red[3] +
                                 red[4] + red[5] + red[6] + red[7]);

  // frag (h, m): At[(h*4)*NDIM + m*16]  (h = half-tile 0..31, k-oct = h*4+oct)
  const unsigned long long* At = g_At + (size_t)oct * NDIM + (brow + wm * 128 + fr);
  const unsigned long long* Bt = g_Bt + (size_t)oct * MDIM + (bcol + wn * 64 + fr);

  f32x4 acc[8][4] = {};
  long Aa0, Aa1, Aa2, Aa3, Aa4, Aa5, Aa6, Aa7, Ab0, Ab1, Ab2, Ab3;  // buf A
  long Ba0, Ba1, Ba2, Ba3, Ba4, Ba5, Ba6, Ba7, Bb0, Bb1, Bb2, Bb3;  // buf B
  long Ca0, Ca1, Ca2, Ca3, Ca4, Ca5, Ca6, Ca7, Cb0, Cb1, Cb2, Cb3;  // buf C

#define LOADH(S, H)                                                          \
  { const unsigned long long* Ap_ = At + (size_t)(H) * 4 * NDIM;             \
    const unsigned long long* Bp_ = Bt + (size_t)(H) * 4 * MDIM;             \
    S##a0 = (long)Ap_[0];   S##a1 = (long)Ap_[16];                           \
    S##a2 = (long)Ap_[32];  S##a3 = (long)Ap_[48];                           \
    S##a4 = (long)Ap_[64];  S##a5 = (long)Ap_[80];                           \
    S##a6 = (long)Ap_[96];  S##a7 = (long)Ap_[112];                          \
    S##b0 = (long)Bp_[0];   S##b1 = (long)Bp_[16];                           \
    S##b2 = (long)Bp_[32];  S##b3 = (long)Bp_[48]; }

#define MFH1(M, AF, S)                                                       \
  acc[M][0] = __builtin_amdgcn_mfma_f32_16x16x32_fp8_fp8(AF, S##b0, acc[M][0], 0, 0, 0); \
  acc[M][1] = __builtin_amdgcn_mfma_f32_16x16x32_fp8_fp8(AF, S##b1, acc[M][1], 0, 0, 0); \
  acc[M][2] = __builtin_amdgcn_mfma_f32_16x16x32_fp8_fp8(AF, S##b2, acc[M][2], 0, 0, 0); \
  acc[M][3] = __builtin_amdgcn_mfma_f32_16x16x32_fp8_fp8(AF, S##b3, acc[M][3], 0, 0, 0);

#define MFH(S)                                                               \
  __builtin_amdgcn_s_setprio(1);                                             \
  MFH1(0, S##a0, S) MFH1(1, S##a1, S) MFH1(2, S##a2, S) MFH1(3, S##a3, S)    \
  MFH1(4, S##a4, S) MFH1(5, S##a5, S) MFH1(6, S##a6, S) MFH1(7, S##a7, S)    \
  __builtin_amdgcn_s_setprio(0);

  // ---- depth-2 software pipeline over 32 half-tiles (buffers A,B,C) ----
  LOADH(A, 0);
  LOADH(B, 1);
  for (int i = 0; i < 10; ++i) {
    int hs = 3 * i;
    LOADH(C, hs + 2);
    MFH(A);
    LOADH(A, hs + 3);
    MFH(B);
    LOADH(B, hs + 4);
    MFH(C);
  }
  MFH(A);
  MFH(B);

  // ---- epilogue: out = s*acc; C/D layout col=lane&15, row=(lane>>4)*4+j ----
  int crow = brow + wm * 128 + (lane >> 4) * 4;
  int ccol = bcol + wn * 64 + (lane & 15);
  #pragma unroll
  for (int mi = 0; mi < 8; ++mi)
    #pragma unroll
    for (int n = 0; n < 4; ++n)
      #pragma unroll
      for (int j = 0; j < 4; ++j)
        C[(size_t)(crow + mi * 16 + j) * MDIM + (ccol + n * 16)] = s_val * acc[mi][n][j];
}

extern "C" void kernel_launch(void* const* d_in, const int* in_sizes, int n_in,
                              void* d_out, int out_size, void* d_ws, size_t ws_size,
                              hipStream_t stream) {
  const float* x     = (const float*)d_in[0];
  const float* y     = (const float*)d_in[1];
  const float* freqs = (const float*)d_in[2];
  const float* lam   = (const float*)d_in[3];
  const float* var   = (const float*)d_in[4];
  float* out = (float*)d_out;

  hipLaunchKernelGGL(phase_kernel, dim3(2048), dim3(256), 0, stream,
                     x, y, freqs, lam);
  hipLaunchKernelGGL(gemm_kernel, dim3((NDIM / 256) * (MDIM / 256)), dim3(512), 0, stream,
                     out, lam, var);
}